// Round 1
// baseline (949.557 us; speedup 1.0000x reference)
//
#include <hip/hip_runtime.h>
#include <math.h>

constexpr int L_LEVELS = 16;
constexpr unsigned TABLE_SIZE = 1u << 19;
constexpr unsigned TMASK = TABLE_SIZE - 1u;

struct EncP {
    float scale[L_LEVELS];
    unsigned res[L_LEVELS];
};

__global__ __launch_bounds__(256) void enc_mlp_kernel(
    const float* __restrict__ x,
    const float* __restrict__ table,
    const float* __restrict__ W1,
    const float* __restrict__ W2,
    const float* __restrict__ W3,
    float* __restrict__ out,
    EncP p)
{
    __shared__ float lds[256 * 33];

    const int tid = threadIdx.x;
    const int n = blockIdx.x * 256 + tid;

    const float x0 = x[n * 3 + 0];
    const float x1 = x[n * 3 + 1];
    const float x2 = x[n * 3 + 2];

    // ---------------- grid encode: 16 levels, 8 corners each ----------------
    float xc[32];
#pragma unroll
    for (int l = 0; l < L_LEVELS; ++l) {
        const float s = p.scale[l];
        const unsigned r = p.res[l];
        const unsigned r2 = r * r;               // uint32 wrap, matches int32 wrap bits

        float px = x0 * s + 0.5f;
        float py = x1 * s + 0.5f;
        float pz = x2 * s + 0.5f;
        float gx = floorf(px), gy = floorf(py), gz = floorf(pz);
        float fx = px - gx, fy = py - gy, fz = pz - gz;
        unsigned ix = (unsigned)(int)gx;
        unsigned iy = (unsigned)(int)gy;
        unsigned iz = (unsigned)(int)gz;
        unsigned base = ix + iy * r + iz * r2;   // wraps like int32

        const float* tl = table + (size_t)l * (size_t)TABLE_SIZE * 2u;
        float a0 = 0.f, a1 = 0.f;
#pragma unroll
        for (int c = 0; c < 8; ++c) {
            // offs row order: i outer (x), then j (y), then k (z)
            const unsigned dx = (c >> 2) & 1u;
            const unsigned dy = (c >> 1) & 1u;
            const unsigned dz = c & 1u;
            unsigned lin = base + dx + dy * r + dz * r2;   // uint32 wrap == int32 wrap
            unsigned idx = lin & TMASK;                    // == python floor-mod 2^19
            const float2 f = *(const float2*)(tl + 2u * idx);
            const float w = (dx ? fx : 1.f - fx) * (dy ? fy : 1.f - fy) * (dz ? fz : 1.f - fz);
            a0 += w * f.x;
            a1 += w * f.y;
        }
        xc[2 * l + 0] = a0;
        xc[2 * l + 1] = a1;
    }

    // ---------------- MLP: 32 -> 64 -> 64 -> 32, ReLU ----------------
    // t_code is all zeros, so only rows 0..31 of W1 matter.
    float h1[64];
#pragma unroll
    for (int j = 0; j < 64; ++j) h1[j] = 0.f;
#pragma unroll
    for (int i = 0; i < 32; ++i) {
        const float v = xc[i];
#pragma unroll
        for (int j = 0; j < 64; ++j) h1[j] = fmaf(v, W1[i * 64 + j], h1[j]);
    }
#pragma unroll
    for (int j = 0; j < 64; ++j) h1[j] = fmaxf(h1[j], 0.f);

    float h2[64];
#pragma unroll
    for (int j = 0; j < 64; ++j) h2[j] = 0.f;
#pragma unroll
    for (int i = 0; i < 64; ++i) {
        const float v = h1[i];
#pragma unroll
        for (int j = 0; j < 64; ++j) h2[j] = fmaf(v, W2[i * 64 + j], h2[j]);
    }
#pragma unroll
    for (int j = 0; j < 64; ++j) h2[j] = fmaxf(h2[j], 0.f);

    float o[32];
#pragma unroll
    for (int j = 0; j < 32; ++j) o[j] = 0.f;
#pragma unroll
    for (int i = 0; i < 64; ++i) {
        const float v = h2[i];
#pragma unroll
        for (int j = 0; j < 32; ++j) o[j] = fmaf(v, W3[i * 32 + j], o[j]);
    }
#pragma unroll
    for (int j = 0; j < 32; ++j) o[j] = fmaxf(o[j], 0.f);

    // ---------------- coalesced store via padded-LDS transpose ----------------
    // write: lane t -> lds[t*33 + j], bank (t+j)%32 -> conflict-free
#pragma unroll
    for (int j = 0; j < 32; ++j) lds[tid * 33 + j] = o[j];
    __syncthreads();

    float* outb = out + (size_t)blockIdx.x * 8192;
#pragma unroll
    for (int k = 0; k < 8; ++k) {
        const int e = k * 1024 + tid * 4;
        float4 v;
        v.x = lds[((e + 0) >> 5) * 33 + ((e + 0) & 31)];
        v.y = lds[((e + 1) >> 5) * 33 + ((e + 1) & 31)];
        v.z = lds[((e + 2) >> 5) * 33 + ((e + 2) & 31)];
        v.w = lds[((e + 3) >> 5) * 33 + ((e + 3) & 31)];
        *(float4*)(outb + e) = v;   // lanes write consecutive 16B: coalesced
    }
}

extern "C" void kernel_launch(void* const* d_in, const int* in_sizes, int n_in,
                              void* d_out, int out_size, void* d_ws, size_t ws_size,
                              hipStream_t stream) {
    (void)in_sizes; (void)n_in; (void)d_ws; (void)ws_size; (void)out_size;

    const float* x     = (const float*)d_in[0];
    // d_in[1] = t : unused (t_code is zeros)
    const float* table = (const float*)d_in[2];
    const float* W1    = (const float*)d_in[3];
    const float* W2    = (const float*)d_in[4];
    const float* W3    = (const float*)d_in[5];
    float* out = (float*)d_out;

    EncP p;
    const double b = exp(log(2048.0 / 16.0) / 15.0);
    for (int l = 0; l < L_LEVELS; ++l) {
        const float s = (float)(16.0 * pow(b, (double)l) - 1.0);  // matches np float32 cast
        p.scale[l] = s;
        p.res[l] = (unsigned)((long long)s) + 1u;                 // matches astype(int64)+1
    }

    hipLaunchKernelGGL(enc_mlp_kernel, dim3(1048576 / 256), dim3(256), 0, stream,
                       x, table, W1, W2, W3, out, p);
}